// Round 4
// baseline (650.301 us; speedup 1.0000x reference)
//
#include <hip/hip_runtime.h>
#include <cstdint>
#include <cstddef>

// Problem constants: B=16, T=4096, D_IN=H=512, L=2, 3H=1536
#define BB 16
#define TT 4096
#define DD 512
#define NG 1536
#define BK 64
#define NCH 64            // chunks per chain
#define CS  (TT / NCH)    // 64 timesteps per chunk
#define NCHAIN (BB * DD)  // 8192 chains

typedef __bf16 bf16x8 __attribute__((ext_vector_type(8)));
typedef float f32x4 __attribute__((ext_vector_type(4)));
typedef unsigned short u16;
typedef __attribute__((ext_vector_type(8))) unsigned short u16x8;

__device__ __forceinline__ u16 f2bf(float f) {
  union { float f; unsigned u; } v; v.f = f;
  return (u16)((v.u + 0x7FFFu + ((v.u >> 16) & 1u)) >> 16);
}
__device__ __forceinline__ float bf2f(u16 s) {
  union { unsigned u; float f; } v; v.u = ((unsigned)s) << 16;
  return v.f;
}
__device__ __forceinline__ float sigm(float x) {
  return 1.f / (1.f + __expf(-x));
}

// async global->LDS, 16B per lane. LDS dest = wave-uniform base + lane*16.
__device__ __forceinline__ void gload_lds16(const void* g, void* l) {
  __builtin_amdgcn_global_load_lds(
      (const __attribute__((address_space(1))) unsigned*)g,
      (__attribute__((address_space(3))) unsigned*)l, 16, 0, 0);
}

// ---------------------------------------------------------------------------
// fp32 -> bf16 bulk convert
// ---------------------------------------------------------------------------
__global__ __launch_bounds__(256) void f32_to_bf16(
    const float* __restrict__ in, u16* __restrict__ out, long n)
{
  const long stride = (long)gridDim.x * 256 * 8;
  for (long i = ((long)blockIdx.x * 256 + threadIdx.x) * 8; i < n; i += stride) {
    float4 a = *reinterpret_cast<const float4*>(in + i);
    float4 b = *reinterpret_cast<const float4*>(in + i + 4);
    uint4 p;
    p.x = (unsigned)f2bf(a.x) | ((unsigned)f2bf(a.y) << 16);
    p.y = (unsigned)f2bf(a.z) | ((unsigned)f2bf(a.w) << 16);
    p.z = (unsigned)f2bf(b.x) | ((unsigned)f2bf(b.y) << 16);
    p.w = (unsigned)f2bf(b.z) | ((unsigned)f2bf(b.w) << 16);
    *reinterpret_cast<uint4*>(out + i) = p;
  }
}

// ---------------------------------------------------------------------------
// GEMM, 256x256 tile, 8-phase schedule (T2+T3+T4+T5).
// gates[m][n] = bias[n] + sum_k A[m][k]*W[n][k]; A,W bf16 ld=512, out bf16.
// 512 threads = 8 waves (2M x 4N). Per wave 128x64 output = 8x4 16x16 frags.
// BK=64 (2 k-subtiles of 32). LDS 128KB: A,B each 2 bufs x 256x64 bf16.
// XOR swizzle: 16B granule g at row r lives at physical granule g^(r&7);
// gload_lds writes linearly so the SOURCE column is pre-swizzled (rule 21).
// Stage schedule (iter i computes kt=2i,2i+1):
//   p1: (2i+1).Ah0  p2: (2i+1).Ah1  p3: (2i+2).Bh0  p4: (2i+2).Bh1 +vmcnt(4)
//   p5: (2i+2).Ah0  p6: (2i+2).Ah1  p7: (2i+3).Bh0  p8: (2i+3).Bh1 +vmcnt(4)
// Region-free proof: B-halves of a buf are last read in phase 2 of its
// 4-phase group, A-halves in phase 3; every stage lands >=1 closing barrier
// after its region's last reader. vmcnt(4) at p4 guarantees kt+1 fully
// landed before p5 reads it; at p8 guarantees kt+2 before next p1.
// ---------------------------------------------------------------------------
__global__ __launch_bounds__(512, 1) void gemm8(
    const u16* __restrict__ A, const u16* __restrict__ W,
    const float* __restrict__ bias, u16* __restrict__ out)
{
  __shared__ __align__(16) u16 As[2][256 * BK];
  __shared__ __align__(16) u16 Bs[2][256 * BK];

  // bijective XCD swizzle (nwg=1536 % 8 == 0); bn fastest so adjacent
  // blocks on one XCD share the A-panel.
  const int cpx = gridDim.x >> 3;
  const int swz = (blockIdx.x & 7) * cpx + (blockIdx.x >> 3);
  const int bm = swz / 6;
  const int bn = swz - bm * 6;

  const int tid = threadIdx.x;
  const int lane = tid & 63;
  const int w = tid >> 6;
  const int wm = w >> 2;           // 0..1
  const int wn = w & 3;            // 0..3
  const int laneM = lane & 15;
  const int laneHi = lane >> 4;    // 0..3

  const long aRow0 = (long)bm * 256;
  const int  bRow0 = bn * 256;

  // staging lane offsets: lane l covers row (l>>3), swizzled source granule
  const int sR = lane >> 3;
  const int sC = ((lane & 7) ^ sR) * 8;   // elements

#define STAGE(gbase, grow0, ldsTile, kt)                                    \
  {                                                                         \
    _Pragma("unroll") for (int c_ = 0; c_ < 2; ++c_) {                      \
      const int rl_ = (c_ * 8 + w) * 8;                                     \
      __builtin_amdgcn_sched_barrier(0);                                    \
      gload_lds16((gbase) + ((long)(grow0) + rl_ + sR) * DD + (kt) * BK + sC, \
                  (ldsTile) + rl_ * BK);                                    \
    }                                                                       \
  }

#define BAR() __builtin_amdgcn_s_barrier()

  f32x4 acc[8][4] = {};
  bf16x8 a[4][2], bl[2][2], bh[2][2];

#define RD_A(MI0, tile)                                                     \
  _Pragma("unroll") for (int q_ = 0; q_ < 4; ++q_) {                        \
    const int r_ = wm * 128 + ((MI0) + q_) * 16 + laneM;                    \
    a[q_][0] = *reinterpret_cast<const bf16x8*>(                            \
        (tile) + r_ * BK + (((0 + laneHi) ^ (r_ & 7)) << 3));               \
    a[q_][1] = *reinterpret_cast<const bf16x8*>(                            \
        (tile) + r_ * BK + (((4 + laneHi) ^ (r_ & 7)) << 3));               \
  }
#define RD_B(dst, NI0, tile)                                                \
  _Pragma("unroll") for (int q_ = 0; q_ < 2; ++q_) {                        \
    const int r_ = wn * 64 + ((NI0) + q_) * 16 + laneM;                     \
    dst[q_][0] = *reinterpret_cast<const bf16x8*>(                          \
        (tile) + r_ * BK + (((0 + laneHi) ^ (r_ & 7)) << 3));               \
    dst[q_][1] = *reinterpret_cast<const bf16x8*>(                          \
        (tile) + r_ * BK + (((4 + laneHi) ^ (r_ & 7)) << 3));               \
  }
#define MFMA_Q(bq, MI0, NI0)                                                \
  __builtin_amdgcn_s_setprio(1);                                            \
  _Pragma("unroll") for (int q_ = 0; q_ < 4; ++q_)                          \
  _Pragma("unroll") for (int r_ = 0; r_ < 2; ++r_) {                        \
    acc[(MI0)+q_][(NI0)+r_] = __builtin_amdgcn_mfma_f32_16x16x32_bf16(      \
        a[q_][0], bq[r_][0], acc[(MI0)+q_][(NI0)+r_], 0, 0, 0);             \
    acc[(MI0)+q_][(NI0)+r_] = __builtin_amdgcn_mfma_f32_16x16x32_bf16(      \
        a[q_][1], bq[r_][1], acc[(MI0)+q_][(NI0)+r_], 0, 0, 0);             \
  }                                                                         \
  __builtin_amdgcn_s_setprio(0);

  // ---- prologue: kt0.B, kt0.A, kt1.B (6 half-tiles, 12 loads/wave)
  STAGE(W, bRow0 + 0,   &Bs[0][0],        0);
  STAGE(W, bRow0 + 128, &Bs[0][128 * BK], 0);
  STAGE(A, aRow0 + 0,   &As[0][0],        0);
  STAGE(A, aRow0 + 128, &As[0][128 * BK], 0);
  STAGE(W, bRow0 + 0,   &Bs[1][0],        1);
  STAGE(W, bRow0 + 128, &Bs[1][128 * BK], 1);
  asm volatile("s_waitcnt vmcnt(4)" ::: "memory");  // kt0 landed
  __builtin_amdgcn_sched_barrier(0);
  BAR();

#pragma unroll
  for (int i = 0; i < 4; ++i) {
    // ---- P1: read buf0 A0-3 + B0-1; stage (2i+1).Ah0
    RD_A(0, As[0]); RD_B(bl, 0, Bs[0]);
    STAGE(A, aRow0 + 0, &As[1][0], 2 * i + 1);
    BAR(); MFMA_Q(bl, 0, 0); BAR();
    // ---- P2: read B2-3; stage (2i+1).Ah1
    RD_B(bh, 2, Bs[0]);
    STAGE(A, aRow0 + 128, &As[1][128 * BK], 2 * i + 1);
    BAR(); MFMA_Q(bh, 0, 2); BAR();
    // ---- P3: read A4-7; stage (2i+2).Bh0
    RD_A(4, As[0]);
    if (i < 3) STAGE(W, bRow0 + 0, &Bs[0][0], 2 * i + 2);
    BAR(); MFMA_Q(bl, 4, 0); BAR();
    // ---- P4: stage (2i+2).Bh1; vmcnt -> kt=2i+1 fully landed
    if (i < 3) {
      STAGE(W, bRow0 + 128, &Bs[0][128 * BK], 2 * i + 2);
      asm volatile("s_waitcnt vmcnt(4)" ::: "memory");
    } else {
      asm volatile("s_waitcnt vmcnt(0)" ::: "memory");
    }
    __builtin_amdgcn_sched_barrier(0);
    BAR(); MFMA_Q(bh, 4, 2); BAR();
    // ---- P5: read buf1 A0-3 + B0-1; stage (2i+2).Ah0
    RD_A(0, As[1]); RD_B(bl, 0, Bs[1]);
    if (i < 3) STAGE(A, aRow0 + 0, &As[0][0], 2 * i + 2);
    BAR(); MFMA_Q(bl, 0, 0); BAR();
    // ---- P6: read B2-3 buf1; stage (2i+2).Ah1
    RD_B(bh, 2, Bs[1]);
    if (i < 3) STAGE(A, aRow0 + 128, &As[0][128 * BK], 2 * i + 2);
    BAR(); MFMA_Q(bh, 0, 2); BAR();
    // ---- P7: read A4-7 buf1; stage (2i+3).Bh0
    RD_A(4, As[1]);
    if (i < 3) STAGE(W, bRow0 + 0, &Bs[1][0], 2 * i + 3);
    BAR(); MFMA_Q(bl, 4, 0); BAR();
    // ---- P8: stage (2i+3).Bh1; vmcnt -> kt=2i+2 fully landed
    if (i < 3) {
      STAGE(W, bRow0 + 128, &Bs[1][128 * BK], 2 * i + 3);
      asm volatile("s_waitcnt vmcnt(4)" ::: "memory");
    }
    __builtin_amdgcn_sched_barrier(0);
    BAR(); MFMA_Q(bh, 4, 2); BAR();
  }

  // epilogue: D row=(lane>>4)*4+r (M), col=lane&15 (N)  [m89/m91]
#pragma unroll
  for (int ni = 0; ni < 4; ++ni) {
    const int n = bn * 256 + wn * 64 + ni * 16 + laneM;
    const float bv = bias[n];
#pragma unroll
    for (int mi = 0; mi < 8; ++mi) {
      const long m = aRow0 + wm * 128 + mi * 16 + laneHi * 4;
#pragma unroll
      for (int r = 0; r < 4; ++r)
        out[(m + r) * (long)NG + n] = f2bf(acc[mi][ni][r] + bv);
    }
  }
#undef STAGE
#undef BAR
#undef RD_A
#undef RD_B
#undef MFMA_Q
}

// ---------------------------------------------------------------------------
// Chunked parallel scan; 8 h-chains per thread, 16B vector gate loads.
// ---------------------------------------------------------------------------
__global__ __launch_bounds__(256) void scan_phase1(
    const u16* __restrict__ gates,
    float* __restrict__ Aout, float* __restrict__ Bout)
{
  const int tid = blockIdx.x * 256 + threadIdx.x;   // 0..65535
  const int cg = tid & 1023;        // b*64 + h8
  const int k  = tid >> 10;
  const int b  = cg >> 6;
  const int h8 = cg & 63;
  const int chain = b * 512 + h8 * 8;

  const u16* g = gates + ((size_t)b * TT + (size_t)k * CS) * NG + h8 * 8;

  float Ac[8], Bc[8];
#pragma unroll
  for (int j = 0; j < 8; ++j) { Ac[j] = 1.f; Bc[j] = 0.f; }

  for (int t = 0; t < CS; t += 4) {
    u16x8 zv[4], fv[4];
#pragma unroll
    for (int u = 0; u < 4; ++u) {
      const u16* gt = g + (size_t)(t + u) * NG;
      zv[u] = *reinterpret_cast<const u16x8*>(gt);
      fv[u] = *reinterpret_cast<const u16x8*>(gt + 512);
    }
#pragma unroll
    for (int u = 0; u < 4; ++u)
#pragma unroll
      for (int j = 0; j < 8; ++j) {
        float z = bf2f(zv[u][j]); z = z > 0.f ? z : 0.f;
        const float f = sigm(bf2f(fv[u][j]));
        Ac[j] = f * Ac[j];
        Bc[j] = f * Bc[j] + (1.f - f) * z;
      }
  }
#pragma unroll
  for (int j = 0; j < 8; ++j) {
    Aout[(size_t)k * NCHAIN + chain + j] = Ac[j];
    Bout[(size_t)k * NCHAIN + chain + j] = Bc[j];
  }
}

__global__ __launch_bounds__(256) void scan_phase2(
    const float* __restrict__ Ain, const float* __restrict__ Bin,
    const float* __restrict__ h0, const int layer,
    float* __restrict__ cstart, float* __restrict__ hout)
{
  const int chain = blockIdx.x * 256 + threadIdx.x;  // 0..8191
  const int b = chain >> 9;
  const int h = chain & 511;

  float c = h0[b * 1024 + layer * 512 + h];
#pragma unroll 8
  for (int k = 0; k < NCH; ++k) {
    cstart[(size_t)k * NCHAIN + chain] = c;
    c = Ain[(size_t)k * NCHAIN + chain] * c + Bin[(size_t)k * NCHAIN + chain];
  }
  hout[b * 1024 + layer * 512 + h] = c;
}

// MODE 0: layer 0 -> write bf16 xb only (fp32 x would be dead).
// MODE 1: layer 1 -> write fp32 x (the final output) only.
template <int MODE>
__global__ __launch_bounds__(256) void scan_phase3(
    const u16* __restrict__ gates, const float* __restrict__ cstart,
    float* __restrict__ xout, u16* __restrict__ xb)
{
  const int tid = blockIdx.x * 256 + threadIdx.x;
  const int cg = tid & 1023;
  const int k  = tid >> 10;
  const int b  = cg >> 6;
  const int h8 = cg & 63;
  const int chain = b * 512 + h8 * 8;

  const u16* g = gates + ((size_t)b * TT + (size_t)k * CS) * NG + h8 * 8;
  const size_t xrow0 = ((size_t)b * TT + (size_t)k * CS) * DD + h8 * 8;

  float c[8];
#pragma unroll
  for (int j = 0; j < 8; ++j) c[j] = cstart[(size_t)k * NCHAIN + chain + j];

  for (int t = 0; t < CS; t += 4) {
    u16x8 zv[4], fv[4], ov[4];
#pragma unroll
    for (int u = 0; u < 4; ++u) {
      const u16* gt = g + (size_t)(t + u) * NG;
      zv[u] = *reinterpret_cast<const u16x8*>(gt);
      fv[u] = *reinterpret_cast<const u16x8*>(gt + 512);
      ov[u] = *reinterpret_cast<const u16x8*>(gt + 1024);
    }
#pragma unroll
    for (int u = 0; u < 4; ++u) {
      float xv[8];
#pragma unroll
      for (int j = 0; j < 8; ++j) {
        float z = bf2f(zv[u][j]); z = z > 0.f ? z : 0.f;
        const float f = sigm(bf2f(fv[u][j]));
        const float o = sigm(bf2f(ov[u][j]));
        c[j] = f * c[j] + (1.f - f) * z;
        xv[j] = o * c[j];
      }
      if (MODE == 0) {
        u16x8 pk;
#pragma unroll
        for (int j = 0; j < 8; ++j) pk[j] = f2bf(xv[j]);
        *reinterpret_cast<u16x8*>(xb + xrow0 + (size_t)(t + u) * DD) = pk;
      } else {
        float* xo = xout + xrow0 + (size_t)(t + u) * DD;
        *reinterpret_cast<float4*>(xo) = make_float4(xv[0], xv[1], xv[2], xv[3]);
        *reinterpret_cast<float4*>(xo + 4) = make_float4(xv[4], xv[5], xv[6], xv[7]);
      }
    }
  }
}

extern "C" void kernel_launch(void* const* d_in, const int* in_sizes, int n_in,
                              void* d_out, int out_size, void* d_ws, size_t ws_size,
                              hipStream_t stream) {
  const float* x  = (const float*)d_in[0];
  const float* h0 = (const float*)d_in[1];
  const float* W0 = (const float*)d_in[2];
  const float* b0 = (const float*)d_in[3];
  const float* W1 = (const float*)d_in[4];
  const float* b1 = (const float*)d_in[5];

  float* out_x = (float*)d_out;                       // [B*T, 512]
  float* out_h = out_x + (size_t)BB * TT * DD;        // [B, 2, 512]

  // workspace layout (~278 MB)
  char* ws = (char*)d_ws;
  u16* gates = (u16*)ws;                              // bf16 [B*T,1536] 201.3MB
  size_t off = (size_t)BB * TT * NG * 2;
  u16* xb  = (u16*)(ws + off);                        // bf16 [B*T,512]  67.1MB
  off += (size_t)BB * TT * DD * 2;
  u16* W0b = (u16*)(ws + off); off += (size_t)NG * DD * 2;
  u16* W1b = (u16*)(ws + off); off += (size_t)NG * DD * 2;
  float* Abuf   = (float*)(ws + off); off += (size_t)NCH * NCHAIN * 4;
  float* Bbuf   = (float*)(ws + off); off += (size_t)NCH * NCHAIN * 4;
  float* cstart = (float*)(ws + off);

  dim3 blk(256);
  dim3 gemmGrid((NG / 256) * ((BB * TT) / 256));      // 6*256 = 1536
  dim3 gemmBlk(512);
  dim3 pGrid((NCHAIN / 8 * NCH) / 256);               // 256
  dim3 p2Grid(NCHAIN / 256);                          // 32

  f32_to_bf16<<<2048, blk, 0, stream>>>(x, xb, (long)BB * TT * DD);
  f32_to_bf16<<<256, blk, 0, stream>>>(W0, W0b, (long)NG * DD);
  f32_to_bf16<<<256, blk, 0, stream>>>(W1, W1b, (long)NG * DD);

  // Layer 0
  gemm8<<<gemmGrid, gemmBlk, 0, stream>>>(xb, W0b, b0, gates);
  scan_phase1<<<pGrid, blk, 0, stream>>>(gates, Abuf, Bbuf);
  scan_phase2<<<p2Grid, blk, 0, stream>>>(Abuf, Bbuf, h0, 0, cstart, out_h);
  scan_phase3<0><<<pGrid, blk, 0, stream>>>(gates, cstart, out_x, xb);
  // Layer 1 (xb rewritten by phase3 only after gemm0 consumed it)
  gemm8<<<gemmGrid, gemmBlk, 0, stream>>>(xb, W1b, b1, gates);
  scan_phase1<<<pGrid, blk, 0, stream>>>(gates, Abuf, Bbuf);
  scan_phase2<<<p2Grid, blk, 0, stream>>>(Abuf, Bbuf, h0, 1, cstart, out_h);
  scan_phase3<1><<<pGrid, blk, 0, stream>>>(gates, cstart, out_x, nullptr);
}

// Round 5
// 479.556 us; speedup vs baseline: 1.3560x; 1.3560x over previous
//
#include <hip/hip_runtime.h>
#include <cstdint>
#include <cstddef>

// Problem constants: B=16, T=4096, D_IN=H=512, L=2, 3H=1536
#define BB 16
#define TT 4096
#define DD 512
#define NG 1536
#define BK 64
#define NCH 64            // chunks per chain
#define CS  (TT / NCH)    // 64 timesteps per chunk
#define NCHAIN (BB * DD)  // 8192 chains

typedef __bf16 bf16x8 __attribute__((ext_vector_type(8)));
typedef float f32x4 __attribute__((ext_vector_type(4)));
typedef unsigned short u16;
typedef __attribute__((ext_vector_type(4))) unsigned short u16x4;

__device__ __forceinline__ u16 f2bf(float f) {
  union { float f; unsigned u; } v; v.f = f;
  return (u16)((v.u + 0x7FFFu + ((v.u >> 16) & 1u)) >> 16);
}
__device__ __forceinline__ float bf2f(u16 s) {
  union { unsigned u; float f; } v; v.u = ((unsigned)s) << 16;
  return v.f;
}
__device__ __forceinline__ float sigm(float x) {
  return 1.f / (1.f + __expf(-x));
}

// async global->LDS, 16B per lane. LDS dest = wave-uniform base + lane*16.
__device__ __forceinline__ void gload_lds16(const void* g, void* l) {
  __builtin_amdgcn_global_load_lds(
      (const __attribute__((address_space(1))) unsigned*)g,
      (__attribute__((address_space(3))) unsigned*)l, 16, 0, 0);
}

// ---------------------------------------------------------------------------
// fp32 -> bf16 bulk convert
// ---------------------------------------------------------------------------
__global__ __launch_bounds__(256) void f32_to_bf16(
    const float* __restrict__ in, u16* __restrict__ out, long n)
{
  const long stride = (long)gridDim.x * 256 * 8;
  for (long i = ((long)blockIdx.x * 256 + threadIdx.x) * 8; i < n; i += stride) {
    float4 a = *reinterpret_cast<const float4*>(in + i);
    float4 b = *reinterpret_cast<const float4*>(in + i + 4);
    uint4 p;
    p.x = (unsigned)f2bf(a.x) | ((unsigned)f2bf(a.y) << 16);
    p.y = (unsigned)f2bf(a.z) | ((unsigned)f2bf(a.w) << 16);
    p.z = (unsigned)f2bf(b.x) | ((unsigned)f2bf(b.y) << 16);
    p.w = (unsigned)f2bf(b.z) | ((unsigned)f2bf(b.w) << 16);
    *reinterpret_cast<uint4*>(out + i) = p;
  }
}

// ---------------------------------------------------------------------------
// GEMM, 256x256 tile, 8-phase schedule (T2+T3+T4+T5) — main loop identical
// to R4 (validated). New: coalesced epilogue via LDS bounce (two 128-row
// passes; 16B/lane global stores -> no partial-line write amplification).
// ---------------------------------------------------------------------------
__global__ __launch_bounds__(512, 1) void gemm8(
    const u16* __restrict__ A, const u16* __restrict__ W,
    const float* __restrict__ bias, u16* __restrict__ out)
{
  __shared__ __align__(16) u16 SMEM[4][256 * BK];   // 128 KB
  u16* const As0 = SMEM[0];
  u16* const As1 = SMEM[1];
  u16* const Bs0 = SMEM[2];
  u16* const Bs1 = SMEM[3];

  // bijective XCD swizzle (nwg=1536 % 8 == 0); bn fastest so adjacent
  // blocks on one XCD share the A-panel.
  const int cpx = gridDim.x >> 3;
  const int swz = (blockIdx.x & 7) * cpx + (blockIdx.x >> 3);
  const int bm = swz / 6;
  const int bn = swz - bm * 6;

  const int tid = threadIdx.x;
  const int lane = tid & 63;
  const int w = tid >> 6;
  const int wm = w >> 2;           // 0..1
  const int wn = w & 3;            // 0..3
  const int laneM = lane & 15;
  const int laneHi = lane >> 4;    // 0..3

  const long aRow0 = (long)bm * 256;
  const int  bRow0 = bn * 256;

  // staging lane offsets: lane l covers row (l>>3), swizzled source granule
  const int sR = lane >> 3;
  const int sC = ((lane & 7) ^ sR) * 8;   // elements

#define STAGE(gbase, grow0, ldsTile, kt)                                    \
  {                                                                         \
    _Pragma("unroll") for (int c_ = 0; c_ < 2; ++c_) {                      \
      const int rl_ = (c_ * 8 + w) * 8;                                     \
      __builtin_amdgcn_sched_barrier(0);                                    \
      gload_lds16((gbase) + ((long)(grow0) + rl_ + sR) * DD + (kt) * BK + sC, \
                  (ldsTile) + rl_ * BK);                                    \
    }                                                                       \
  }

#define BAR() __builtin_amdgcn_s_barrier()

  f32x4 acc[8][4] = {};
  bf16x8 a[4][2], bl[2][2], bh[2][2];

#define RD_A(MI0, tile)                                                     \
  _Pragma("unroll") for (int q_ = 0; q_ < 4; ++q_) {                        \
    const int r_ = wm * 128 + ((MI0) + q_) * 16 + laneM;                    \
    a[q_][0] = *reinterpret_cast<const bf16x8*>(                            \
        (tile) + r_ * BK + (((0 + laneHi) ^ (r_ & 7)) << 3));               \
    a[q_][1] = *reinterpret_cast<const bf16x8*>(                            \
        (tile) + r_ * BK + (((4 + laneHi) ^ (r_ & 7)) << 3));               \
  }
#define RD_B(dst, NI0, tile)                                                \
  _Pragma("unroll") for (int q_ = 0; q_ < 2; ++q_) {                        \
    const int r_ = wn * 64 + ((NI0) + q_) * 16 + laneM;                     \
    dst[q_][0] = *reinterpret_cast<const bf16x8*>(                          \
        (tile) + r_ * BK + (((0 + laneHi) ^ (r_ & 7)) << 3));               \
    dst[q_][1] = *reinterpret_cast<const bf16x8*>(                          \
        (tile) + r_ * BK + (((4 + laneHi) ^ (r_ & 7)) << 3));               \
  }
#define MFMA_Q(bq, MI0, NI0)                                                \
  __builtin_amdgcn_s_setprio(1);                                            \
  _Pragma("unroll") for (int q_ = 0; q_ < 4; ++q_)                          \
  _Pragma("unroll") for (int r_ = 0; r_ < 2; ++r_) {                        \
    acc[(MI0)+q_][(NI0)+r_] = __builtin_amdgcn_mfma_f32_16x16x32_bf16(      \
        a[q_][0], bq[r_][0], acc[(MI0)+q_][(NI0)+r_], 0, 0, 0);             \
    acc[(MI0)+q_][(NI0)+r_] = __builtin_amdgcn_mfma_f32_16x16x32_bf16(      \
        a[q_][1], bq[r_][1], acc[(MI0)+q_][(NI0)+r_], 0, 0, 0);             \
  }                                                                         \
  __builtin_amdgcn_s_setprio(0);

  // ---- prologue: kt0.B, kt0.A, kt1.B (6 half-tiles, 12 loads/wave)
  STAGE(W, bRow0 + 0,   Bs0,            0);
  STAGE(W, bRow0 + 128, Bs0 + 128 * BK, 0);
  STAGE(A, aRow0 + 0,   As0,            0);
  STAGE(A, aRow0 + 128, As0 + 128 * BK, 0);
  STAGE(W, bRow0 + 0,   Bs1,            1);
  STAGE(W, bRow0 + 128, Bs1 + 128 * BK, 1);
  asm volatile("s_waitcnt vmcnt(4)" ::: "memory");  // kt0 landed
  __builtin_amdgcn_sched_barrier(0);
  BAR();

#pragma unroll
  for (int i = 0; i < 4; ++i) {
    // ---- P1: read buf0 A0-3 + B0-1; stage (2i+1).Ah0
    RD_A(0, As0); RD_B(bl, 0, Bs0);
    STAGE(A, aRow0 + 0, As1, 2 * i + 1);
    BAR(); MFMA_Q(bl, 0, 0); BAR();
    // ---- P2: read B2-3; stage (2i+1).Ah1
    RD_B(bh, 2, Bs0);
    STAGE(A, aRow0 + 128, As1 + 128 * BK, 2 * i + 1);
    BAR(); MFMA_Q(bh, 0, 2); BAR();
    // ---- P3: read A4-7; stage (2i+2).Bh0
    RD_A(4, As0);
    if (i < 3) STAGE(W, bRow0 + 0, Bs0, 2 * i + 2);
    BAR(); MFMA_Q(bl, 4, 0); BAR();
    // ---- P4: stage (2i+2).Bh1; vmcnt -> kt=2i+1 fully landed
    if (i < 3) {
      STAGE(W, bRow0 + 128, Bs0 + 128 * BK, 2 * i + 2);
      asm volatile("s_waitcnt vmcnt(4)" ::: "memory");
    } else {
      asm volatile("s_waitcnt vmcnt(0)" ::: "memory");
    }
    __builtin_amdgcn_sched_barrier(0);
    BAR(); MFMA_Q(bh, 4, 2); BAR();
    // ---- P5: read buf1 A0-3 + B0-1; stage (2i+2).Ah0
    RD_A(0, As1); RD_B(bl, 0, Bs1);
    if (i < 3) STAGE(A, aRow0 + 0, As0, 2 * i + 2);
    BAR(); MFMA_Q(bl, 0, 0); BAR();
    // ---- P6: read B2-3 buf1; stage (2i+2).Ah1
    RD_B(bh, 2, Bs1);
    if (i < 3) STAGE(A, aRow0 + 128, As0 + 128 * BK, 2 * i + 2);
    BAR(); MFMA_Q(bh, 0, 2); BAR();
    // ---- P7: read A4-7 buf1; stage (2i+3).Bh0
    RD_A(4, As1);
    if (i < 3) STAGE(W, bRow0 + 0, Bs1, 2 * i + 3);
    BAR(); MFMA_Q(bl, 4, 0); BAR();
    // ---- P8: stage (2i+3).Bh1; vmcnt -> kt=2i+2 fully landed
    if (i < 3) {
      STAGE(W, bRow0 + 128, Bs1 + 128 * BK, 2 * i + 3);
      asm volatile("s_waitcnt vmcnt(4)" ::: "memory");
    }
    __builtin_amdgcn_sched_barrier(0);
    BAR(); MFMA_Q(bh, 4, 2); BAR();
  }

  // ---- epilogue: LDS bounce, two 128-row passes, 16B/lane coalesced stores.
  // acc layout: row = wm*128 + mi*16 + laneHi*4 + r, col = wn*64 + ni*16 + laneM.
  float bvv[4];
#pragma unroll
  for (int ni = 0; ni < 4; ++ni)
    bvv[ni] = bias[bn * 256 + wn * 64 + ni * 16 + laneM];

  u16* const ep = &SMEM[0][0];          // 128x264 u16 = 67.6 KB used
#define EPS 264                          // row stride (u16), +8 pad
#pragma unroll
  for (int p = 0; p < 2; ++p) {
    if (p) BAR();                        // pass-0 readers done before overwrite
    if (wm == p) {
#pragma unroll
      for (int mi = 0; mi < 8; ++mi)
#pragma unroll
        for (int ni = 0; ni < 4; ++ni)
#pragma unroll
          for (int r = 0; r < 4; ++r)
            ep[(mi * 16 + laneHi * 4 + r) * EPS + wn * 64 + ni * 16 + laneM] =
                f2bf(acc[mi][ni][r] + bvv[ni]);
    }
    asm volatile("s_waitcnt lgkmcnt(0)" ::: "memory");  // cross-wave visible
    __builtin_amdgcn_sched_barrier(0);
    BAR();
#pragma unroll
    for (int it = 0; it < 8; ++it) {
      const int row = (tid >> 5) + it * 16;           // 0..127
      const int col8 = (tid & 31) * 8;                // 0..248
      uint4 v = *reinterpret_cast<const uint4*>(&ep[row * EPS + col8]);
      *reinterpret_cast<uint4*>(
          &out[(aRow0 + p * 128 + row) * (long)NG + bn * 256 + col8]) = v;
    }
  }
#undef EPS
#undef STAGE
#undef BAR
#undef RD_A
#undef RD_B
#undef MFMA_Q
}

// ---------------------------------------------------------------------------
// Chunked parallel scan; 4 h-chains per thread (8B vector loads),
// 131072 threads = 8 waves/CU.
// ---------------------------------------------------------------------------
__global__ __launch_bounds__(256) void scan_phase1(
    const u16* __restrict__ gates,
    float* __restrict__ Aout, float* __restrict__ Bout)
{
  const int tid = blockIdx.x * 256 + threadIdx.x;   // 0..131071
  const int cg = tid & 2047;        // b*128 + h4
  const int k  = tid >> 11;
  const int b  = cg >> 7;
  const int h4 = cg & 127;
  const int chain = b * 512 + h4 * 4;

  const u16* g = gates + ((size_t)b * TT + (size_t)k * CS) * NG + h4 * 4;

  float Ac[4], Bc[4];
#pragma unroll
  for (int j = 0; j < 4; ++j) { Ac[j] = 1.f; Bc[j] = 0.f; }

  for (int t = 0; t < CS; t += 4) {
    u16x4 zv[4], fv[4];
#pragma unroll
    for (int u = 0; u < 4; ++u) {
      const u16* gt = g + (size_t)(t + u) * NG;
      zv[u] = *reinterpret_cast<const u16x4*>(gt);
      fv[u] = *reinterpret_cast<const u16x4*>(gt + 512);
    }
#pragma unroll
    for (int u = 0; u < 4; ++u)
#pragma unroll
      for (int j = 0; j < 4; ++j) {
        float z = bf2f(zv[u][j]); z = z > 0.f ? z : 0.f;
        const float f = sigm(bf2f(fv[u][j]));
        Ac[j] = f * Ac[j];
        Bc[j] = f * Bc[j] + (1.f - f) * z;
      }
  }
#pragma unroll
  for (int j = 0; j < 4; ++j) {
    Aout[(size_t)k * NCHAIN + chain + j] = Ac[j];
    Bout[(size_t)k * NCHAIN + chain + j] = Bc[j];
  }
}

__global__ __launch_bounds__(256) void scan_phase2(
    const float* __restrict__ Ain, const float* __restrict__ Bin,
    const float* __restrict__ h0, const int layer,
    float* __restrict__ cstart, float* __restrict__ hout)
{
  const int chain = blockIdx.x * 256 + threadIdx.x;  // 0..8191
  const int b = chain >> 9;
  const int h = chain & 511;

  float c = h0[b * 1024 + layer * 512 + h];
#pragma unroll 8
  for (int k = 0; k < NCH; ++k) {
    cstart[(size_t)k * NCHAIN + chain] = c;
    c = Ain[(size_t)k * NCHAIN + chain] * c + Bin[(size_t)k * NCHAIN + chain];
  }
  hout[b * 1024 + layer * 512 + h] = c;
}

// MODE 0: layer 0 -> write bf16 xb only (fp32 x would be dead).
// MODE 1: layer 1 -> write fp32 x (the final output) only.
template <int MODE>
__global__ __launch_bounds__(256) void scan_phase3(
    const u16* __restrict__ gates, const float* __restrict__ cstart,
    float* __restrict__ xout, u16* __restrict__ xb)
{
  const int tid = blockIdx.x * 256 + threadIdx.x;
  const int cg = tid & 2047;
  const int k  = tid >> 11;
  const int b  = cg >> 7;
  const int h4 = cg & 127;
  const int chain = b * 512 + h4 * 4;

  const u16* g = gates + ((size_t)b * TT + (size_t)k * CS) * NG + h4 * 4;
  const size_t xrow0 = ((size_t)b * TT + (size_t)k * CS) * DD + h4 * 4;

  float c[4];
#pragma unroll
  for (int j = 0; j < 4; ++j) c[j] = cstart[(size_t)k * NCHAIN + chain + j];

  for (int t = 0; t < CS; t += 4) {
    u16x4 zv[4], fv[4], ov[4];
#pragma unroll
    for (int u = 0; u < 4; ++u) {
      const u16* gt = g + (size_t)(t + u) * NG;
      zv[u] = *reinterpret_cast<const u16x4*>(gt);
      fv[u] = *reinterpret_cast<const u16x4*>(gt + 512);
      ov[u] = *reinterpret_cast<const u16x4*>(gt + 1024);
    }
#pragma unroll
    for (int u = 0; u < 4; ++u) {
      float xv[4];
#pragma unroll
      for (int j = 0; j < 4; ++j) {
        float z = bf2f(zv[u][j]); z = z > 0.f ? z : 0.f;
        const float f = sigm(bf2f(fv[u][j]));
        const float o = sigm(bf2f(ov[u][j]));
        c[j] = f * c[j] + (1.f - f) * z;
        xv[j] = o * c[j];
      }
      if (MODE == 0) {
        u16x4 pk;
#pragma unroll
        for (int j = 0; j < 4; ++j) pk[j] = f2bf(xv[j]);
        *reinterpret_cast<u16x4*>(xb + xrow0 + (size_t)(t + u) * DD) = pk;
      } else {
        *reinterpret_cast<float4*>(xout + xrow0 + (size_t)(t + u) * DD) =
            make_float4(xv[0], xv[1], xv[2], xv[3]);
      }
    }
  }
}

extern "C" void kernel_launch(void* const* d_in, const int* in_sizes, int n_in,
                              void* d_out, int out_size, void* d_ws, size_t ws_size,
                              hipStream_t stream) {
  const float* x  = (const float*)d_in[0];
  const float* h0 = (const float*)d_in[1];
  const float* W0 = (const float*)d_in[2];
  const float* b0 = (const float*)d_in[3];
  const float* W1 = (const float*)d_in[4];
  const float* b1 = (const float*)d_in[5];

  float* out_x = (float*)d_out;                       // [B*T, 512]
  float* out_h = out_x + (size_t)BB * TT * DD;        // [B, 2, 512]

  // workspace layout (~278 MB, same high-water as R3/R4)
  char* ws = (char*)d_ws;
  u16* gates = (u16*)ws;                              // bf16 [B*T,1536] 201.3MB
  size_t off = (size_t)BB * TT * NG * 2;
  u16* xb  = (u16*)(ws + off);                        // bf16 [B*T,512]  67.1MB
  off += (size_t)BB * TT * DD * 2;
  u16* W0b = (u16*)(ws + off); off += (size_t)NG * DD * 2;
  u16* W1b = (u16*)(ws + off); off += (size_t)NG * DD * 2;
  float* Abuf   = (float*)(ws + off); off += (size_t)NCH * NCHAIN * 4;
  float* Bbuf   = (float*)(ws + off); off += (size_t)NCH * NCHAIN * 4;
  float* cstart = (float*)(ws + off);

  dim3 blk(256);
  dim3 gemmGrid((NG / 256) * ((BB * TT) / 256));      // 6*256 = 1536
  dim3 gemmBlk(512);
  dim3 pGrid((NCHAIN / 4 * NCH) / 256);               // 512 blocks
  dim3 p2Grid(NCHAIN / 256);                          // 32

  f32_to_bf16<<<2048, blk, 0, stream>>>(x, xb, (long)BB * TT * DD);
  f32_to_bf16<<<256, blk, 0, stream>>>(W0, W0b, (long)NG * DD);
  f32_to_bf16<<<256, blk, 0, stream>>>(W1, W1b, (long)NG * DD);

  // Layer 0
  gemm8<<<gemmGrid, gemmBlk, 0, stream>>>(xb, W0b, b0, gates);
  scan_phase1<<<pGrid, blk, 0, stream>>>(gates, Abuf, Bbuf);
  scan_phase2<<<p2Grid, blk, 0, stream>>>(Abuf, Bbuf, h0, 0, cstart, out_h);
  scan_phase3<0><<<pGrid, blk, 0, stream>>>(gates, cstart, out_x, xb);
  // Layer 1 (xb rewritten by phase3 only after gemm0 consumed it)
  gemm8<<<gemmGrid, gemmBlk, 0, stream>>>(xb, W1b, b1, gates);
  scan_phase1<<<pGrid, blk, 0, stream>>>(gates, Abuf, Bbuf);
  scan_phase2<<<p2Grid, blk, 0, stream>>>(Abuf, Bbuf, h0, 1, cstart, out_h);
  scan_phase3<1><<<pGrid, blk, 0, stream>>>(gates, cstart, out_x, nullptr);
}

// Round 7
// 470.384 us; speedup vs baseline: 1.3825x; 1.0195x over previous
//
#include <hip/hip_runtime.h>
#include <cstdint>
#include <cstddef>

// Problem constants: B=16, T=4096, D_IN=H=512, L=2, 3H=1536
#define BB 16
#define TT 4096
#define DD 512
#define NG 1536
#define NCH 64            // chunks per chain
#define CS  (TT / NCH)    // 64 timesteps per chunk
#define NCHAIN (BB * DD)  // 8192 chains

typedef __bf16 bf16x8 __attribute__((ext_vector_type(8)));
typedef float f32x4 __attribute__((ext_vector_type(4)));
typedef unsigned short u16;
typedef __attribute__((ext_vector_type(4))) unsigned short u16x4;

__device__ __forceinline__ u16 f2bf(float f) {
  union { float f; unsigned u; } v; v.f = f;
  return (u16)((v.u + 0x7FFFu + ((v.u >> 16) & 1u)) >> 16);
}
__device__ __forceinline__ float bf2f(u16 s) {
  union { unsigned u; float f; } v; v.u = ((unsigned)s) << 16;
  return v.f;
}
__device__ __forceinline__ float sigm(float x) {
  return 1.f / (1.f + __expf(-x));
}

// async global->LDS, 16B per lane. LDS dest = wave-uniform base + lane*16.
__device__ __forceinline__ void gload_lds16(const void* g, void* l) {
  __builtin_amdgcn_global_load_lds(
      (const __attribute__((address_space(1))) unsigned*)g,
      (__attribute__((address_space(3))) unsigned*)l, 16, 0, 0);
}

// ---------------------------------------------------------------------------
// fp32 -> bf16 bulk convert
// ---------------------------------------------------------------------------
__global__ __launch_bounds__(256) void f32_to_bf16(
    const float* __restrict__ in, u16* __restrict__ out, long n)
{
  const long stride = (long)gridDim.x * 256 * 8;
  for (long i = ((long)blockIdx.x * 256 + threadIdx.x) * 8; i < n; i += stride) {
    float4 a = *reinterpret_cast<const float4*>(in + i);
    float4 b = *reinterpret_cast<const float4*>(in + i + 4);
    uint4 p;
    p.x = (unsigned)f2bf(a.x) | ((unsigned)f2bf(a.y) << 16);
    p.y = (unsigned)f2bf(a.z) | ((unsigned)f2bf(a.w) << 16);
    p.z = (unsigned)f2bf(b.x) | ((unsigned)f2bf(b.y) << 16);
    p.w = (unsigned)f2bf(b.z) | ((unsigned)f2bf(b.w) << 16);
    *reinterpret_cast<uint4*>(out + i) = p;
  }
}

// ---------------------------------------------------------------------------
// GEMM: gates[m][n] = bias[n] + sum_k A[m][k]*W[n][k]; A,W bf16 ld=512.
// 128x256 tile, BK=32, 512 thr = 8 waves (2M x 4N), 64x64 per wave
// (acc = 64 VGPR -> 2 blocks/CU = 16 waves/CU; independent barrier domains
// so one block's MFMA covers the other's stage/barrier stalls).
// Per kt: {stage kt+1 (3 gloads), counted vmcnt(3), BAR, 8 ds_read_b128,
// 16 MFMA under setprio, BAR}  x16 fully unrolled.
// B tile is 256x32 = 8192 u16: rows 0-127 at bbuf+0, rows 128-255 at
// bbuf+4096  (R6 bug: was +8192 -> clobbered the other buffer).
// ---------------------------------------------------------------------------
__global__ __launch_bounds__(512, 4) void gemmW(
    const u16* __restrict__ A, const u16* __restrict__ W,
    const float* __restrict__ bias, u16* __restrict__ out)
{
  __shared__ __align__(16) u16 SMEM[128 * 280];   // 70 KB; main loop uses 48 KB
  u16* const Ab0 = SMEM;                // 128x32
  u16* const Ab1 = SMEM + 4096;
  u16* const Bb0 = SMEM + 8192;         // 256x32
  u16* const Bb1 = SMEM + 16384;

  // bijective XCD swizzle (nwg = 3072, %8==0); bn fastest within a chunk so
  // blocks sharing the A-panel land on the same XCD.
  const int cpx = gridDim.x >> 3;
  const int swz = (blockIdx.x & 7) * cpx + (blockIdx.x >> 3);
  const int bm = swz / 6;               // 0..511 (M tiles of 128)
  const int bn = swz - bm * 6;          // 0..5   (N tiles of 256)

  const int tid = threadIdx.x;
  const int lane = tid & 63;
  const int w = tid >> 6;
  const int wm = w >> 2;                // 0..1  (64-row band)
  const int wn = w & 3;                 // 0..3  (64-col band)
  const int laneM = lane & 15;
  const int laneHi = lane >> 4;         // 0..3 -> k-granule

  const long mRow0 = (long)bm * 128;
  const int  nRow0 = bn * 256;          // W rows (= gate cols)

  // staging: thread t covers LDS granule t: row = t>>2, col granule = t&3
  const int sRow = tid >> 2;            // 0..127
  const int sCol = (tid & 3) * 8;       // elements
  const int wOff = w * 512;             // wave-uniform LDS u16 offset

  const u16* const aSrc = A + (mRow0 + sRow) * DD + sCol;
  const u16* const bSrc0 = W + (long)(nRow0 + sRow) * DD + sCol;
  const u16* const bSrc1 = W + (long)(nRow0 + 128 + sRow) * DD + sCol;

#define STAGE(kt, abuf, bbuf)                                               \
  gload_lds16(aSrc + (kt) * 32, (abuf) + wOff);                             \
  gload_lds16(bSrc0 + (kt) * 32, (bbuf) + wOff);                            \
  gload_lds16(bSrc1 + (kt) * 32, (bbuf) + 4096 + wOff);

#define BAR() __builtin_amdgcn_s_barrier()

  f32x4 acc[4][4] = {};

  // prologue: stage kt=0 into buf0
  STAGE(0, Ab0, Bb0);

  const int aOff = (wm * 64 + laneM) * 32 + laneHi * 8;   // + q*512
  const int bOff = (wn * 64 + laneM) * 32 + laneHi * 8;   // + r*512

#pragma unroll
  for (int kt = 0; kt < 16; ++kt) {
    const u16* const Abuf = (kt & 1) ? Ab1 : Ab0;
    const u16* const Bbuf = (kt & 1) ? Bb1 : Bb0;
    u16* const AbufN = (kt & 1) ? Ab0 : Ab1;
    u16* const BbufN = (kt & 1) ? Bb0 : Bb1;

    if (kt < 15) {
      STAGE(kt + 1, AbufN, BbufN);
      asm volatile("s_waitcnt vmcnt(3)" ::: "memory");
    } else {
      asm volatile("s_waitcnt vmcnt(0)" ::: "memory");
    }
    __builtin_amdgcn_sched_barrier(0);
    BAR();

    bf16x8 a[4], b[4];
#pragma unroll
    for (int q = 0; q < 4; ++q)
      a[q] = *reinterpret_cast<const bf16x8*>(&Abuf[aOff + q * 512]);
#pragma unroll
    for (int r = 0; r < 4; ++r)
      b[r] = *reinterpret_cast<const bf16x8*>(&Bbuf[bOff + r * 512]);

    __builtin_amdgcn_s_setprio(1);
#pragma unroll
    for (int q = 0; q < 4; ++q)
#pragma unroll
      for (int r = 0; r < 4; ++r)
        acc[q][r] = __builtin_amdgcn_mfma_f32_16x16x32_bf16(
            a[q], b[r], acc[q][r], 0, 0, 0);
    __builtin_amdgcn_s_setprio(0);
    BAR();
  }

  // ---- epilogue: LDS bounce (EPS=280 -> 16B-aligned rows), coalesced
  // 16B/lane stores (validated in R5: kills write amplification).
  float bvv[4];
#pragma unroll
  for (int ni = 0; ni < 4; ++ni)
    bvv[ni] = bias[nRow0 + wn * 64 + ni * 16 + laneM];

#define EPS 280
  u16* const ep = SMEM;
#pragma unroll
  for (int mi = 0; mi < 4; ++mi)
#pragma unroll
    for (int ni = 0; ni < 4; ++ni)
#pragma unroll
      for (int r = 0; r < 4; ++r)
        ep[(wm * 64 + mi * 16 + laneHi * 4 + r) * EPS +
           wn * 64 + ni * 16 + laneM] = f2bf(acc[mi][ni][r] + bvv[ni]);
  asm volatile("s_waitcnt lgkmcnt(0)" ::: "memory");
  __builtin_amdgcn_sched_barrier(0);
  BAR();

#pragma unroll
  for (int it = 0; it < 8; ++it) {
    const int row = tid >> 2;                       // 0..127
    const int col = ((tid & 3) + it * 4) * 8;       // 0..248 (u16)
    uint4 v = *reinterpret_cast<const uint4*>(&ep[row * EPS + col]);
    *reinterpret_cast<uint4*>(
        &out[(mRow0 + row) * (long)NG + nRow0 + col]) = v;
  }
#undef EPS
#undef STAGE
#undef BAR
}

// ---------------------------------------------------------------------------
// Chunked parallel scan; 4 h-chains per thread (8B vector loads),
// 131072 threads = 8 waves/CU. (unchanged from R5, validated)
// ---------------------------------------------------------------------------
__global__ __launch_bounds__(256) void scan_phase1(
    const u16* __restrict__ gates,
    float* __restrict__ Aout, float* __restrict__ Bout)
{
  const int tid = blockIdx.x * 256 + threadIdx.x;   // 0..131071
  const int cg = tid & 2047;        // b*128 + h4
  const int k  = tid >> 11;
  const int b  = cg >> 7;
  const int h4 = cg & 127;
  const int chain = b * 512 + h4 * 4;

  const u16* g = gates + ((size_t)b * TT + (size_t)k * CS) * NG + h4 * 4;

  float Ac[4], Bc[4];
#pragma unroll
  for (int j = 0; j < 4; ++j) { Ac[j] = 1.f; Bc[j] = 0.f; }

  for (int t = 0; t < CS; t += 4) {
    u16x4 zv[4], fv[4];
#pragma unroll
    for (int u = 0; u < 4; ++u) {
      const u16* gt = g + (size_t)(t + u) * NG;
      zv[u] = *reinterpret_cast<const u16x4*>(gt);
      fv[u] = *reinterpret_cast<const u16x4*>(gt + 512);
    }
#pragma unroll
    for (int u = 0; u < 4; ++u)
#pragma unroll
      for (int j = 0; j < 4; ++j) {
        float z = bf2f(zv[u][j]); z = z > 0.f ? z : 0.f;
        const float f = sigm(bf2f(fv[u][j]));
        Ac[j] = f * Ac[j];
        Bc[j] = f * Bc[j] + (1.f - f) * z;
      }
  }
#pragma unroll
  for (int j = 0; j < 4; ++j) {
    Aout[(size_t)k * NCHAIN + chain + j] = Ac[j];
    Bout[(size_t)k * NCHAIN + chain + j] = Bc[j];
  }
}

__global__ __launch_bounds__(256) void scan_phase2(
    const float* __restrict__ Ain, const float* __restrict__ Bin,
    const float* __restrict__ h0, const int layer,
    float* __restrict__ cstart, float* __restrict__ hout)
{
  const int chain = blockIdx.x * 256 + threadIdx.x;  // 0..8191
  const int b = chain >> 9;
  const int h = chain & 511;

  float c = h0[b * 1024 + layer * 512 + h];
#pragma unroll 8
  for (int k = 0; k < NCH; ++k) {
    cstart[(size_t)k * NCHAIN + chain] = c;
    c = Ain[(size_t)k * NCHAIN + chain] * c + Bin[(size_t)k * NCHAIN + chain];
  }
  hout[b * 1024 + layer * 512 + h] = c;
}

// MODE 0: layer 0 -> write bf16 xb only (fp32 x would be dead).
// MODE 1: layer 1 -> write fp32 x (the final output) only.
template <int MODE>
__global__ __launch_bounds__(256) void scan_phase3(
    const u16* __restrict__ gates, const float* __restrict__ cstart,
    float* __restrict__ xout, u16* __restrict__ xb)
{
  const int tid = blockIdx.x * 256 + threadIdx.x;
  const int cg = tid & 2047;
  const int k  = tid >> 11;
  const int b  = cg >> 7;
  const int h4 = cg & 127;
  const int chain = b * 512 + h4 * 4;

  const u16* g = gates + ((size_t)b * TT + (size_t)k * CS) * NG + h4 * 4;
  const size_t xrow0 = ((size_t)b * TT + (size_t)k * CS) * DD + h4 * 4;

  float c[4];
#pragma unroll
  for (int j = 0; j < 4; ++j) c[j] = cstart[(size_t)k * NCHAIN + chain + j];

  for (int t = 0; t < CS; t += 4) {
    u16x4 zv[4], fv[4], ov[4];
#pragma unroll
    for (int u = 0; u < 4; ++u) {
      const u16* gt = g + (size_t)(t + u) * NG;
      zv[u] = *reinterpret_cast<const u16x4*>(gt);
      fv[u] = *reinterpret_cast<const u16x4*>(gt + 512);
      ov[u] = *reinterpret_cast<const u16x4*>(gt + 1024);
    }
#pragma unroll
    for (int u = 0; u < 4; ++u) {
      float xv[4];
#pragma unroll
      for (int j = 0; j < 4; ++j) {
        float z = bf2f(zv[u][j]); z = z > 0.f ? z : 0.f;
        const float f = sigm(bf2f(fv[u][j]));
        const float o = sigm(bf2f(ov[u][j]));
        c[j] = f * c[j] + (1.f - f) * z;
        xv[j] = o * c[j];
      }
      if (MODE == 0) {
        u16x4 pk;
#pragma unroll
        for (int j = 0; j < 4; ++j) pk[j] = f2bf(xv[j]);
        *reinterpret_cast<u16x4*>(xb + xrow0 + (size_t)(t + u) * DD) = pk;
      } else {
        *reinterpret_cast<float4*>(xout + xrow0 + (size_t)(t + u) * DD) =
            make_float4(xv[0], xv[1], xv[2], xv[3]);
      }
    }
  }
}

extern "C" void kernel_launch(void* const* d_in, const int* in_sizes, int n_in,
                              void* d_out, int out_size, void* d_ws, size_t ws_size,
                              hipStream_t stream) {
  const float* x  = (const float*)d_in[0];
  const float* h0 = (const float*)d_in[1];
  const float* W0 = (const float*)d_in[2];
  const float* b0 = (const float*)d_in[3];
  const float* W1 = (const float*)d_in[4];
  const float* b1 = (const float*)d_in[5];

  float* out_x = (float*)d_out;                       // [B*T, 512]
  float* out_h = out_x + (size_t)BB * TT * DD;        // [B, 2, 512]

  // workspace layout (~278 MB, same as R5)
  char* ws = (char*)d_ws;
  u16* gates = (u16*)ws;                              // bf16 [B*T,1536] 201.3MB
  size_t off = (size_t)BB * TT * NG * 2;
  u16* xb  = (u16*)(ws + off);                        // bf16 [B*T,512]  67.1MB
  off += (size_t)BB * TT * DD * 2;
  u16* W0b = (u16*)(ws + off); off += (size_t)NG * DD * 2;
  u16* W1b = (u16*)(ws + off); off += (size_t)NG * DD * 2;
  float* Abuf   = (float*)(ws + off); off += (size_t)NCH * NCHAIN * 4;
  float* Bbuf   = (float*)(ws + off); off += (size_t)NCH * NCHAIN * 4;
  float* cstart = (float*)(ws + off);

  dim3 blk(256);
  dim3 gemmGrid((NG / 256) * ((BB * TT) / 128));      // 6*512 = 3072
  dim3 gemmBlk(512);
  dim3 pGrid((NCHAIN / 4 * NCH) / 256);               // 512 blocks
  dim3 p2Grid(NCHAIN / 256);                          // 32

  f32_to_bf16<<<2048, blk, 0, stream>>>(x, xb, (long)BB * TT * DD);
  f32_to_bf16<<<256, blk, 0, stream>>>(W0, W0b, (long)NG * DD);
  f32_to_bf16<<<256, blk, 0, stream>>>(W1, W1b, (long)NG * DD);

  // Layer 0
  gemmW<<<gemmGrid, gemmBlk, 0, stream>>>(xb, W0b, b0, gates);
  scan_phase1<<<pGrid, blk, 0, stream>>>(gates, Abuf, Bbuf);
  scan_phase2<<<p2Grid, blk, 0, stream>>>(Abuf, Bbuf, h0, 0, cstart, out_h);
  scan_phase3<0><<<pGrid, blk, 0, stream>>>(gates, cstart, out_x, xb);
  // Layer 1 (xb rewritten by phase3 only after gemm0 consumed it)
  gemmW<<<gemmGrid, gemmBlk, 0, stream>>>(xb, W1b, b1, gates);
  scan_phase1<<<pGrid, blk, 0, stream>>>(gates, Abuf, Bbuf);
  scan_phase2<<<p2Grid, blk, 0, stream>>>(Abuf, Bbuf, h0, 1, cstart, out_h);
  scan_phase3<1><<<pGrid, blk, 0, stream>>>(gates, cstart, out_x, nullptr);
}